// Round 14
// baseline (488.278 us; speedup 1.0000x reference)
//
#include <hip/hip_runtime.h>
#include <stdint.h>

// W8A16 quantized linear, two-phase:
//   Pre-pass: A f32->f16 (64 MB), W = fp16(q*scale) (32 MB) into d_ws.
//   GEMM:     256x256 tile, BK=32, 8 waves (2M x 4N), wave tile 128x64.
//             NEW: B (weights) never touches LDS — each lane's B-fragment is
//             16 contiguous bytes of the row-major panel, loaded directly
//             global->VGPR (L2-resident; XCD swizzle pins one 2 MB tn-panel
//             per XCD). A stays LDS-staged (packed-pair XOR layout,
//             HW-verified R13). Single barrier per K-tile; B regs
//             double-buffered by name; 1-tile slack makes the end-of-tile
//             vmcnt(0) drain temporally free (L3-resident, ~300 cyc lat).
// Why: R5-R13 (six schedule variants) all measured = MFMA + total-LDS-
//   traffic, fully serial (79-89 cyc/K-unit). Removing B's LDS read+write
//   cuts the serial floor ~30% (2841 -> ~2000 cyc/tile) independent of
//   scheduling.
// Regs: acc 128 AGPR + arch ~80 (af 32, bA/bB 32, offsets) -> no spill.

#define M_DIM 8192
#define N_DIM 4096
#define K_DIM 4096
#define BM 256
#define BN 256
#define BK 32
#define NKT (K_DIM / BK)   // 128 K-tiles

typedef _Float16 f16;
typedef f16 f16x8 __attribute__((ext_vector_type(8)));
typedef f16 f16x2 __attribute__((ext_vector_type(2)));
typedef float f32x4 __attribute__((ext_vector_type(4)));

static __device__ __forceinline__ f16x2 cvt2(float a, float b) {
  return __builtin_bit_cast(f16x2, __builtin_amdgcn_cvt_pkrtz(a, b));
}

// ---------------- pre-pass kernels ----------------

__global__ __launch_bounds__(256) void conv_a_kernel(
    const float* __restrict__ A, f16* __restrict__ Af)
{
  const size_t stride = (size_t)gridDim.x * blockDim.x;
  size_t i = (size_t)blockIdx.x * blockDim.x + threadIdx.x;
  const size_t n8 = (size_t)M_DIM * K_DIM / 8;
  for (; i < n8; i += stride) {
    const f32x4* p = (const f32x4*)(A + i * 8);
    f32x4 v0 = p[0], v1 = p[1];
    f16x2 a = cvt2(v0.x, v0.y), b = cvt2(v0.z, v0.w);
    f16x2 c = cvt2(v1.x, v1.y), d = cvt2(v1.z, v1.w);
    *(f16x8*)(Af + i * 8) = (f16x8){a.x, a.y, b.x, b.y, c.x, c.y, d.x, d.y};
  }
}

__global__ __launch_bounds__(256) void conv_b_kernel(
    const int* __restrict__ Qw, const float* __restrict__ Sc,
    f16* __restrict__ Wf)
{
  const int o = blockIdx.x;
  const int t = threadIdx.x;
  const float s = Sc[o];
  const int* q = Qw + (size_t)o * K_DIM + t * 16;
  f16* w = Wf + (size_t)o * K_DIM + t * 16;
  #pragma unroll
  for (int h = 0; h < 2; ++h) {
    int4 u0 = *(const int4*)(q + h * 8);
    int4 u1 = *(const int4*)(q + h * 8 + 4);
    f16x2 a = cvt2((float)u0.x * s, (float)u0.y * s);
    f16x2 b = cvt2((float)u0.z * s, (float)u0.w * s);
    f16x2 c = cvt2((float)u1.x * s, (float)u1.y * s);
    f16x2 d = cvt2((float)u1.z * s, (float)u1.w * s);
    *(f16x8*)(w + h * 8) = (f16x8){a.x, a.y, b.x, b.y, c.x, c.y, d.x, d.y};
  }
}

// ---------------- main GEMM ----------------

#define BARX() __builtin_amdgcn_s_barrier()
#define SCHED0() __builtin_amdgcn_sched_barrier(0)
#define VMW0() do { asm volatile("s_waitcnt vmcnt(0)" ::: "memory"); \
                    __builtin_amdgcn_sched_barrier(0); } while (0)

// stage one 256x32 f16 A-tile (16 KB): 2 x global_load_lds(16B)/thread,
// linear LDS dest, inverse-mapped global source (packed-pair XOR layout)
#define STAGE_A(bi, ktn) do { \
  _Pragma("unroll") \
  for (int _i = 0; _i < 2; ++_i) { \
    const f16* _g = aSrc + (size_t)((st_R + 64 * _i) * 2 + st_h) * K_DIM \
                    + (ktn) * BK + st_s * 8; \
    char* _l = (char*)&As[bi][0] + _i * 8192 + wid * 1024; \
    __builtin_amdgcn_global_load_lds( \
        (const __attribute__((address_space(1))) void*)_g, \
        (__attribute__((address_space(3))) void*)_l, 16, 0, 0); \
  } } while (0)

// A fragment reads: base offset + compile-time immediate (R13-verified)
#define A_LDS(CB, j) (const f16x8*)((const char*)&As[CB][0] + aoff + 2048 * (j))

// One K-tile. CURB/NXTB: A LDS buffers; BCUR/BNXT: named B reg sets.
#define TILE(KT, CURB, NXTB, BCUR, BNXT, M1) do { \
  if (M1) { \
    const f16* _bk = bSrc + (size_t)((KT) + 1) * BK; \
    BNXT[0] = *(const f16x8*)(_bk + bo0); \
    BNXT[1] = *(const f16x8*)(_bk + bo1); \
    BNXT[2] = *(const f16x8*)(_bk + bo2); \
    BNXT[3] = *(const f16x8*)(_bk + bo3); \
    STAGE_A(NXTB, (KT) + 1); \
  } \
  _Pragma("unroll") \
  for (int _j = 0; _j < 8; ++_j) af[_j] = *A_LDS(CURB, _j); \
  _Pragma("unroll") \
  for (int _m = 0; _m < 8; ++_m) \
    _Pragma("unroll") \
    for (int _n = 0; _n < 4; ++_n) \
      acc[_m][_n] = __builtin_amdgcn_mfma_f32_16x16x32_f16( \
          af[_m], BCUR[_n], acc[_m][_n], 0, 0, 0); \
  VMW0(); \
  BARX(); \
} while (0)

__global__ __launch_bounds__(512, 1) void w8a16_gemm_f16_kernel(
    const f16* __restrict__ Af,   // [M][K]
    const f16* __restrict__ Wf,   // [N][K], scale folded
    float* __restrict__ Out)      // [M][N]
{
  // A only: 2 buffers x 16 KB = 32 KB LDS
  __shared__ __align__(16) f16 As[2][BM * BK];

  const int t    = threadIdx.x;
  const int lane = t & 63;
  const int wid  = t >> 6;       // 0..7
  const int wm   = wid >> 2;     // 0..1 (M interleave)
  const int wn   = wid & 3;      // 0..3 (N interleave)
  const int fr   = lane & 15;
  const int qk   = lane >> 4;    // k-slot 0..3

  // A staging map (thread t, inst i): phys slot f = t + i*512;
  // L=f>>3, w'=f&7, w=w'^(L&7): row=(st_R+64i)*2+st_h, k-slot st_s
  const int st_R = t >> 3;
  const int st_x = (t & 7) ^ (st_R & 7);
  const int st_h = st_x >> 2;
  const int st_s = st_x & 3;

  // A fragment read base (packed-pair XOR layout); frag j -> +2048j bytes
  const int ca   = wm * 16 + fr;
  const int aoff = (ca >> 1) * 128
                 + (((((ca & 1) << 2) | qk) ^ ((ca >> 1) & 7)) << 4);

  // B per-lane element offsets (row-major panel, 16B contiguous per frag)
  const uint32_t bo0 = (uint32_t)((0 * 64 + wn * 16 + fr) * K_DIM + qk * 8);
  const uint32_t bo1 = (uint32_t)((1 * 64 + wn * 16 + fr) * K_DIM + qk * 8);
  const uint32_t bo2 = (uint32_t)((2 * 64 + wn * 16 + fr) * K_DIM + qk * 8);
  const uint32_t bo3 = (uint32_t)((3 * 64 + wn * 16 + fr) * K_DIM + qk * 8);

  // XCD swizzle: 512 blocks; concurrent blocks on one XCD share tn
  // (B panel 2 MB pinned in that XCD's L2) while tm sweeps.
  const int bid = blockIdx.x;
  const int swz = (bid & 7) * 64 + (bid >> 3);
  const int tn  = swz >> 5;      // 16 N-tiles (fixed per XCD per round)
  const int tm  = swz & 31;      // 32 M-tiles

  const f16* aSrc = Af + (size_t)tm * BM * K_DIM;   // block-uniform -> SGPR
  const f16* bSrc = Wf + (size_t)tn * BN * K_DIM;

  f32x4 acc[8][4] = {};
  f16x8 af[8], bA[4], bB[4];

  // prologue: B(0) -> bA; stage A(0) -> As[0]; seal
  {
    const f16* _bk = bSrc;
    bA[0] = *(const f16x8*)(_bk + bo0);
    bA[1] = *(const f16x8*)(_bk + bo1);
    bA[2] = *(const f16x8*)(_bk + bo2);
    bA[3] = *(const f16x8*)(_bk + bo3);
  }
  STAGE_A(0, 0);
  VMW0();
  BARX();
  SCHED0();

  // hot loop: pairs of tiles, B regs ping-pong by name
  for (int kt = 0; kt < NKT - 2; kt += 2) {
    TILE(kt,     0, 1, bA, bB, 1);
    TILE(kt + 1, 1, 0, bB, bA, 1);
  }
  TILE(NKT - 2, 0, 1, bA, bB, 1);
  TILE(NKT - 1, 1, 0, bB, bA, 0);

  // epilogue: C/D col = lane&15, row = (lane>>4)*4 + reg
  const int fq = lane >> 4;
  #pragma unroll
  for (int mi = 0; mi < 8; ++mi) {
    const size_t row = (size_t)tm * BM + (2 * mi + wm) * 16 + fq * 4;
    #pragma unroll
    for (int ni = 0; ni < 4; ++ni) {
      const size_t col = (size_t)tn * BN + ni * 64 + wn * 16 + fr;
      #pragma unroll
      for (int r = 0; r < 4; ++r)
        Out[(row + r) * N_DIM + col] = acc[mi][ni][r];
    }
  }
}

// ---------------- fallback (round-3 verified path) ----------------

__global__ __launch_bounds__(256) void w8a16_gemm_fb_kernel(
    const float* __restrict__ A, const int* __restrict__ Qw,
    const float* __restrict__ Sc, float* __restrict__ Out)
{
  __shared__ __align__(16) float Asf[2][128 * 32];
  __shared__ __align__(16) f16 Bsf[2][128][32];

  const int t = threadIdx.x, lane = t & 63, wid = t >> 6;
  const int wr = wid >> 1, wc = wid & 1;
  const int nwg = gridDim.x, cpx = nwg >> 3, bid = blockIdx.x;
  const int swz = (bid & 7) * cpx + (bid >> 3);
  const int tn = swz & 31, tm = swz >> 5;
  const size_t a_base = (size_t)tm * 128 * K_DIM;
  const size_t b_base = (size_t)tn * 128 * K_DIM;
  f32x4 acc[4][4] = {};
  const int a_r = t >> 3;
  const int a_slog = (t & 7) ^ ((t >> 3) & 7);

  auto stageA = [&](int buf, int kt) {
    #pragma unroll
    for (int c = 0; c < 4; ++c) {
      const float* g = A + a_base + (size_t)(c * 32 + a_r) * K_DIM + kt * 32 + a_slog * 4;
      char* l = (char*)&Asf[buf][0] + c * 4096 + wid * 1024;
      __builtin_amdgcn_global_load_lds(
          (const __attribute__((address_space(1))) void*)g,
          (__attribute__((address_space(3))) void*)l, 16, 0, 0);
    }
  };
  const int b_r = t >> 3, b_col = (t & 7) * 4;
  auto loadB = [&](int kt, int4* v) {
    #pragma unroll
    for (int c = 0; c < 4; ++c)
      v[c] = *(const int4*)(Qw + b_base + (size_t)(c * 32 + b_r) * K_DIM + kt * 32 + b_col);
  };
  auto writeB = [&](int buf, const int4* v) {
    #pragma unroll
    for (int c = 0; c < 4; ++c) {
      f16x2 lo = cvt2((float)v[c].x, (float)v[c].y);
      f16x2 hi = cvt2((float)v[c].z, (float)v[c].w);
      *(f16x2*)&Bsf[buf][c * 32 + b_r][b_col] = lo;
      *(f16x2*)&Bsf[buf][c * 32 + b_r][b_col + 2] = hi;
    }
  };
  auto compute = [&](int buf) {
    const int fr2 = lane & 15, q = lane >> 4;
    f16x8 af2[4], bf2[4];
    #pragma unroll
    for (int i = 0; i < 4; ++i) {
      const int r = wr * 64 + i * 16 + fr2;
      const float* base = &Asf[buf][0] + r * 32;
      const int s0 = q * 2;
      f32x4 a0 = *(const f32x4*)(base + ((s0 ^ (r & 7)) * 4));
      f32x4 a1 = *(const f32x4*)(base + (((s0 + 1) ^ (r & 7)) * 4));
      f16x2 p0 = cvt2(a0.x, a0.y), p1 = cvt2(a0.z, a0.w);
      f16x2 p2 = cvt2(a1.x, a1.y), p3 = cvt2(a1.z, a1.w);
      af2[i] = (f16x8){p0.x, p0.y, p1.x, p1.y, p2.x, p2.y, p3.x, p3.y};
      bf2[i] = *(const f16x8*)&Bsf[buf][wc * 64 + i * 16 + fr2][q * 8];
    }
    #pragma unroll
    for (int mi = 0; mi < 4; ++mi)
      #pragma unroll
      for (int ni = 0; ni < 4; ++ni)
        acc[mi][ni] = __builtin_amdgcn_mfma_f32_16x16x32_f16(
            af2[mi], bf2[ni], acc[mi][ni], 0, 0, 0);
  };

  { int4 b0[4]; stageA(0, 0); loadB(0, b0); writeB(0, b0); }
  __syncthreads();
  for (int kt = 0; kt < K_DIM / 32; ++kt) {
    const int buf = kt & 1;
    const bool more = (kt + 1) < K_DIM / 32;
    int4 nb[4];
    if (more) { stageA(buf ^ 1, kt + 1); loadB(kt + 1, nb); }
    compute(buf);
    if (more) writeB(buf ^ 1, nb);
    __syncthreads();
  }
  const int fr2 = lane & 15, fq = lane >> 4;
  const int cb = tn * 128 + wc * 64 + fr2;
  const int rb = tm * 128 + wr * 64 + fq * 4;
  #pragma unroll
  for (int ni = 0; ni < 4; ++ni) {
    const float s = Sc[cb + ni * 16];
    #pragma unroll
    for (int mi = 0; mi < 4; ++mi)
      #pragma unroll
      for (int r = 0; r < 4; ++r)
        Out[(size_t)(rb + mi * 16 + r) * N_DIM + (cb + ni * 16)] =
            acc[mi][ni][r] * s;
  }
}

extern "C" void kernel_launch(void* const* d_in, const int* in_sizes, int n_in,
                              void* d_out, int out_size, void* d_ws, size_t ws_size,
                              hipStream_t stream) {
  const float* A  = (const float*)d_in[0];
  const int*   Qw = (const int*)d_in[1];
  const float* Sc = (const float*)d_in[2];
  float*       Out = (float*)d_out;

  const size_t a_bytes = (size_t)M_DIM * K_DIM * sizeof(f16);  // 64 MB
  const size_t w_bytes = (size_t)N_DIM * K_DIM * sizeof(f16);  // 32 MB

  if (ws_size >= a_bytes + w_bytes) {
    f16* Af = (f16*)d_ws;
    f16* Wf = (f16*)((char*)d_ws + a_bytes);
    conv_a_kernel<<<2048, 256, 0, stream>>>(A, Af);
    conv_b_kernel<<<N_DIM, 256, 0, stream>>>(Qw, Sc, Wf);
    dim3 grid((M_DIM / BM) * (N_DIM / BN));  // 32*16 = 512
    w8a16_gemm_f16_kernel<<<grid, 512, 0, stream>>>(Af, Wf, Out);
  } else {
    dim3 grid((M_DIM / 128) * (N_DIM / 128));
    w8a16_gemm_fb_kernel<<<grid, 256, 0, stream>>>(A, Qw, Sc, Out);
  }
}

// Round 15
// 352.863 us; speedup vs baseline: 1.3838x; 1.3838x over previous
//
#include <hip/hip_runtime.h>
#include <stdint.h>

// W8A16 quantized linear, two-phase:
//   Pre-pass: A f32->f16 row-major (64 MB); W = fp16(q*scale) in a
//             FRAGMENT-TILED layout Wf2 (32 MB): for each (c16 = col/16,
//             kt = k/32) fragment, the 64 lanes' 16B chunks stored
//             contiguously (1 KB, lane l = qk*16+fr holds
//             W[c16*16+fr][kt*32+qk*8..+8]).
//   GEMM:     256x256 tile, BK=32, 8 waves (2M x 4N), wave tile 128x64.
//             B read DIRECTLY global->VGPR from Wf2 — coalesced 1KB/inst
//             (fixes R14's 64-line/inst gather, which caused FETCH 674MB
//             and 462us). A stays LDS-staged (R13 packed-pair XOR layout,
//             HW-verified). One barrier/tile; split LGKM(4)/LGKM(0) so the
//             second MFMA half covers the tail reads; VMW(4) seals only
//             the A-stage (B loads drain under compiler dep-waits with a
//             full tile of slack, L2-resident).
// Serial model (validated on R13: 1242+1152+~450 = 2841 cyc/tile == 303us):
//   now 1242 MFMA + 768 A-reads + ~130 writes + sync, B on the TA path.
// Regs: acc 128 AGPR + arch ~104 (R14 measured, no spill).

#define M_DIM 8192
#define N_DIM 4096
#define K_DIM 4096
#define BM 256
#define BN 256
#define BK 32
#define NKT (K_DIM / BK)   // 128 K-tiles

typedef _Float16 f16;
typedef f16 f16x8 __attribute__((ext_vector_type(8)));
typedef f16 f16x2 __attribute__((ext_vector_type(2)));
typedef float f32x4 __attribute__((ext_vector_type(4)));

static __device__ __forceinline__ f16x2 cvt2(float a, float b) {
  return __builtin_bit_cast(f16x2, __builtin_amdgcn_cvt_pkrtz(a, b));
}

// ---------------- pre-pass kernels ----------------

__global__ __launch_bounds__(256) void conv_a_kernel(
    const float* __restrict__ A, f16* __restrict__ Af)
{
  const size_t stride = (size_t)gridDim.x * blockDim.x;
  size_t i = (size_t)blockIdx.x * blockDim.x + threadIdx.x;
  const size_t n8 = (size_t)M_DIM * K_DIM / 8;
  for (; i < n8; i += stride) {
    const f32x4* p = (const f32x4*)(A + i * 8);
    f32x4 v0 = p[0], v1 = p[1];
    f16x2 a = cvt2(v0.x, v0.y), b = cvt2(v0.z, v0.w);
    f16x2 c = cvt2(v1.x, v1.y), d = cvt2(v1.z, v1.w);
    *(f16x8*)(Af + i * 8) = (f16x8){a.x, a.y, b.x, b.y, c.x, c.y, d.x, d.y};
  }
}

// W -> fragment-tiled Wf2. Block = c16 (0..255), thread t: l=t&63, g=t>>6.
// Lane l holds (fr=l&15, qk=l>>4); row o = c16*16+fr; iterates kt = g+4j.
// Write elem index ((c16*128+kt)*64+l)*8  -> wave-coalesced 16B stores.
__global__ __launch_bounds__(256) void conv_b2_kernel(
    const int* __restrict__ Qw, const float* __restrict__ Sc,
    f16* __restrict__ Wf2)
{
  const int c16 = blockIdx.x;
  const int t  = threadIdx.x;
  const int l  = t & 63;
  const int g  = t >> 6;          // 0..3
  const int fr = l & 15;
  const int qk = l >> 4;
  const int o  = c16 * 16 + fr;
  const float s = Sc[o];
  const int* qrow = Qw + (size_t)o * K_DIM + qk * 8;
  f16* wbase = Wf2 + (size_t)c16 * 128 * 64 * 8 + (size_t)l * 8;
  for (int kt = g; kt < NKT; kt += 4) {
    const int* q = qrow + kt * 32;
    int4 u0 = *(const int4*)(q);
    int4 u1 = *(const int4*)(q + 4);
    f16x2 a = cvt2((float)u0.x * s, (float)u0.y * s);
    f16x2 b = cvt2((float)u0.z * s, (float)u0.w * s);
    f16x2 c = cvt2((float)u1.x * s, (float)u1.y * s);
    f16x2 d = cvt2((float)u1.z * s, (float)u1.w * s);
    *(f16x8*)(wbase + (size_t)kt * 512) =
        (f16x8){a.x, a.y, b.x, b.y, c.x, c.y, d.x, d.y};
  }
}

// ---------------- main GEMM ----------------

#define BARX() __builtin_amdgcn_s_barrier()
#define SCHED0() __builtin_amdgcn_sched_barrier(0)
#define LGKM(n) do { asm volatile("s_waitcnt lgkmcnt(" #n ")" ::: "memory"); \
                     __builtin_amdgcn_sched_barrier(0); } while (0)
#define VMW(n)  do { asm volatile("s_waitcnt vmcnt(" #n ")" ::: "memory"); \
                     __builtin_amdgcn_sched_barrier(0); } while (0)

// stage one 256x32 f16 A-tile (16 KB): 2 x global_load_lds(16B)/thread,
// linear LDS dest, inverse-mapped global source (packed-pair XOR layout)
#define STAGE_A(bi, ktn) do { \
  _Pragma("unroll") \
  for (int _i = 0; _i < 2; ++_i) { \
    const f16* _g = aSrc + (size_t)((st_R + 64 * _i) * 2 + st_h) * K_DIM \
                    + (ktn) * BK + st_s * 8; \
    char* _l = (char*)&As[bi][0] + _i * 8192 + wid * 1024; \
    __builtin_amdgcn_global_load_lds( \
        (const __attribute__((address_space(1))) void*)_g, \
        (__attribute__((address_space(3))) void*)_l, 16, 0, 0); \
  } } while (0)

// A fragment reads: base offset + compile-time immediate (R13-verified)
#define A_LDS(CB, j) (const f16x8*)((const char*)&As[CB][0] + aoff + 2048 * (j))

// coalesced B fragment loads from Wf2: frag ni at +ni*524288, tile +kt*1024
#define LOAD_B(dst, ktn) do { \
  dst[0] = *(const f16x8*)(bbase + 0 * 524288 + (size_t)(ktn) * 1024); \
  dst[1] = *(const f16x8*)(bbase + 1 * 524288 + (size_t)(ktn) * 1024); \
  dst[2] = *(const f16x8*)(bbase + 2 * 524288 + (size_t)(ktn) * 1024); \
  dst[3] = *(const f16x8*)(bbase + 3 * 524288 + (size_t)(ktn) * 1024); \
  } while (0)

// 16 MFMA: m-frags mb..mb+3 x 4 n-frags
#define MFMA4(mb, B_) do { \
  _Pragma("unroll") \
  for (int _m = 0; _m < 4; ++_m) \
    _Pragma("unroll") \
    for (int _n = 0; _n < 4; ++_n) \
      acc[(mb) + _m][_n] = __builtin_amdgcn_mfma_f32_16x16x32_f16( \
          af[(mb) + _m], B_[_n], acc[(mb) + _m][_n], 0, 0, 0); \
  } while (0)

// One K-tile. CUR/NXT: A LDS buffers; BCUR/BNXT: named B reg sets.
#define TILE(KT, CUR, NXT, BCUR, BNXT, M1) do { \
  if (M1) { \
    STAGE_A(NXT, (KT) + 1); \
    LOAD_B(BNXT, (KT) + 1); \
  } \
  af[0] = *A_LDS(CUR, 0); af[1] = *A_LDS(CUR, 1); \
  af[2] = *A_LDS(CUR, 2); af[3] = *A_LDS(CUR, 3); \
  af[4] = *A_LDS(CUR, 4); af[5] = *A_LDS(CUR, 5); \
  af[6] = *A_LDS(CUR, 6); af[7] = *A_LDS(CUR, 7); \
  LGKM(4); \
  MFMA4(0, BCUR); \
  LGKM(0); \
  MFMA4(4, BCUR); \
  if (M1) { VMW(4); } else { VMW(0); } \
  BARX(); \
} while (0)

__global__ __launch_bounds__(512, 1) void w8a16_gemm_f16_kernel(
    const f16* __restrict__ Af,   // [M][K] row-major
    const f16* __restrict__ Wf2,  // fragment-tiled (scale folded)
    float* __restrict__ Out)      // [M][N]
{
  // A only: 2 buffers x 16 KB = 32 KB LDS
  __shared__ __align__(16) f16 As[2][BM * BK];

  const int t    = threadIdx.x;
  const int lane = t & 63;
  const int wid  = t >> 6;       // 0..7
  const int wm   = wid >> 2;     // 0..1 (M interleave)
  const int wn   = wid & 3;      // 0..3 (N interleave)
  const int fr   = lane & 15;
  const int qk   = lane >> 4;    // k-slot 0..3

  // A staging map (R13): phys slot f = t + i*512; L=f>>3, w'=f&7,
  // w = w'^(L&7): row = (st_R+64i)*2+st_h, k-slot st_s
  const int st_R = t >> 3;
  const int st_x = (t & 7) ^ (st_R & 7);
  const int st_h = st_x >> 2;
  const int st_s = st_x & 3;

  // A fragment read base (packed-pair XOR layout); frag j -> +2048j bytes
  const int ca   = wm * 16 + fr;
  const int aoff = (ca >> 1) * 128
                 + (((((ca & 1) << 2) | qk) ^ ((ca >> 1) & 7)) << 4);

  // XCD swizzle: 512 blocks; concurrent blocks on one XCD share tn
  // (B panel 2 MB pinned in that XCD's L2) while tm sweeps.
  const int bid = blockIdx.x;
  const int swz = (bid & 7) * 64 + (bid >> 3);
  const int tn  = swz >> 5;      // 16 N-tiles
  const int tm  = swz & 31;      // 32 M-tiles

  const f16* aSrc = Af + (size_t)tm * BM * K_DIM;   // block-uniform -> SGPR

  // B base: c16 = tn*16 + ni*4 + wn; byte((ni,kt),lane) =
  //   (c16*128 + kt)*1024 + lane*16
  const char* bbase = (const char*)Wf2
      + ((size_t)(tn * 16 + wn) * 128) * 1024 + (size_t)lane * 16;

  f32x4 acc[8][4] = {};
  f16x8 af[8], bA[4], bB[4];

  // prologue: stage A(0); load B(0); VMW(4) retires the 2 stage insts
  // (issued first); compiler dep-waits cover bA before first MFMA.
  STAGE_A(0, 0);
  LOAD_B(bA, 0);
  VMW(4);
  BARX();
  SCHED0();

  for (int kt = 0; kt < NKT - 2; kt += 2) {
    TILE(kt,     0, 1, bA, bB, 1);
    TILE(kt + 1, 1, 0, bB, bA, 1);
  }
  TILE(NKT - 2, 0, 1, bA, bB, 1);
  TILE(NKT - 1, 1, 0, bB, bA, 0);

  // epilogue: C/D col = lane&15, row = (lane>>4)*4 + reg
  const int fq = lane >> 4;
  #pragma unroll
  for (int mi = 0; mi < 8; ++mi) {
    const size_t row = (size_t)tm * BM + (2 * mi + wm) * 16 + fq * 4;
    #pragma unroll
    for (int ni = 0; ni < 4; ++ni) {
      const size_t col = (size_t)tn * BN + ni * 64 + wn * 16 + fr;
      #pragma unroll
      for (int r = 0; r < 4; ++r)
        Out[(row + r) * N_DIM + col] = acc[mi][ni][r];
    }
  }
}

// ---------------- fallback (round-3 verified path) ----------------

__global__ __launch_bounds__(256) void w8a16_gemm_fb_kernel(
    const float* __restrict__ A, const int* __restrict__ Qw,
    const float* __restrict__ Sc, float* __restrict__ Out)
{
  __shared__ __align__(16) float Asf[2][128 * 32];
  __shared__ __align__(16) f16 Bsf[2][128][32];

  const int t = threadIdx.x, lane = t & 63, wid = t >> 6;
  const int wr = wid >> 1, wc = wid & 1;
  const int nwg = gridDim.x, cpx = nwg >> 3, bid = blockIdx.x;
  const int swz = (bid & 7) * cpx + (bid >> 3);
  const int tn = swz & 31, tm = swz >> 5;
  const size_t a_base = (size_t)tm * 128 * K_DIM;
  const size_t b_base = (size_t)tn * 128 * K_DIM;
  f32x4 acc[4][4] = {};
  const int a_r = t >> 3;
  const int a_slog = (t & 7) ^ ((t >> 3) & 7);

  auto stageA = [&](int buf, int kt) {
    #pragma unroll
    for (int c = 0; c < 4; ++c) {
      const float* g = A + a_base + (size_t)(c * 32 + a_r) * K_DIM + kt * 32 + a_slog * 4;
      char* l = (char*)&Asf[buf][0] + c * 4096 + wid * 1024;
      __builtin_amdgcn_global_load_lds(
          (const __attribute__((address_space(1))) void*)g,
          (__attribute__((address_space(3))) void*)l, 16, 0, 0);
    }
  };
  const int b_r = t >> 3, b_col = (t & 7) * 4;
  auto loadB = [&](int kt, int4* v) {
    #pragma unroll
    for (int c = 0; c < 4; ++c)
      v[c] = *(const int4*)(Qw + b_base + (size_t)(c * 32 + b_r) * K_DIM + kt * 32 + b_col);
  };
  auto writeB = [&](int buf, const int4* v) {
    #pragma unroll
    for (int c = 0; c < 4; ++c) {
      f16x2 lo = cvt2((float)v[c].x, (float)v[c].y);
      f16x2 hi = cvt2((float)v[c].z, (float)v[c].w);
      *(f16x2*)&Bsf[buf][c * 32 + b_r][b_col] = lo;
      *(f16x2*)&Bsf[buf][c * 32 + b_r][b_col + 2] = hi;
    }
  };
  auto compute = [&](int buf) {
    const int fr2 = lane & 15, q = lane >> 4;
    f16x8 af2[4], bf2[4];
    #pragma unroll
    for (int i = 0; i < 4; ++i) {
      const int r = wr * 64 + i * 16 + fr2;
      const float* base = &Asf[buf][0] + r * 32;
      const int s0 = q * 2;
      f32x4 a0 = *(const f32x4*)(base + ((s0 ^ (r & 7)) * 4));
      f32x4 a1 = *(const f32x4*)(base + (((s0 + 1) ^ (r & 7)) * 4));
      f16x2 p0 = cvt2(a0.x, a0.y), p1 = cvt2(a0.z, a0.w);
      f16x2 p2 = cvt2(a1.x, a1.y), p3 = cvt2(a1.z, a1.w);
      af2[i] = (f16x8){p0.x, p0.y, p1.x, p1.y, p2.x, p2.y, p3.x, p3.y};
      bf2[i] = *(const f16x8*)&Bsf[buf][wc * 64 + i * 16 + fr2][q * 8];
    }
    #pragma unroll
    for (int mi = 0; mi < 4; ++mi)
      #pragma unroll
      for (int ni = 0; ni < 4; ++ni)
        acc[mi][ni] = __builtin_amdgcn_mfma_f32_16x16x32_f16(
            af2[mi], bf2[ni], acc[mi][ni], 0, 0, 0);
  };

  { int4 b0[4]; stageA(0, 0); loadB(0, b0); writeB(0, b0); }
  __syncthreads();
  for (int kt = 0; kt < K_DIM / 32; ++kt) {
    const int buf = kt & 1;
    const bool more = (kt + 1) < K_DIM / 32;
    int4 nb[4];
    if (more) { stageA(buf ^ 1, kt + 1); loadB(kt + 1, nb); }
    compute(buf);
    if (more) writeB(buf ^ 1, nb);
    __syncthreads();
  }
  const int fr2 = lane & 15, fq = lane >> 4;
  const int cb = tn * 128 + wc * 64 + fr2;
  const int rb = tm * 128 + wr * 64 + fq * 4;
  #pragma unroll
  for (int ni = 0; ni < 4; ++ni) {
    const float s = Sc[cb + ni * 16];
    #pragma unroll
    for (int mi = 0; mi < 4; ++mi)
      #pragma unroll
      for (int r = 0; r < 4; ++r)
        Out[(size_t)(rb + mi * 16 + r) * N_DIM + (cb + ni * 16)] =
            acc[mi][ni][r] * s;
  }
}

extern "C" void kernel_launch(void* const* d_in, const int* in_sizes, int n_in,
                              void* d_out, int out_size, void* d_ws, size_t ws_size,
                              hipStream_t stream) {
  const float* A  = (const float*)d_in[0];
  const int*   Qw = (const int*)d_in[1];
  const float* Sc = (const float*)d_in[2];
  float*       Out = (float*)d_out;

  const size_t a_bytes = (size_t)M_DIM * K_DIM * sizeof(f16);  // 64 MB
  const size_t w_bytes = (size_t)N_DIM * K_DIM * sizeof(f16);  // 32 MB

  if (ws_size >= a_bytes + w_bytes) {
    f16* Af  = (f16*)d_ws;
    f16* Wf2 = (f16*)((char*)d_ws + a_bytes);
    conv_a_kernel<<<2048, 256, 0, stream>>>(A, Af);
    conv_b2_kernel<<<N_DIM / 16, 256, 0, stream>>>(Qw, Sc, Wf2);
    dim3 grid((M_DIM / BM) * (N_DIM / BN));  // 32*16 = 512
    w8a16_gemm_f16_kernel<<<grid, 512, 0, stream>>>(Af, Wf2, Out);
  } else {
    dim3 grid((M_DIM / 128) * (N_DIM / 128));
    w8a16_gemm_fb_kernel<<<grid, 256, 0, stream>>>(A, Qw, Sc, Out);
  }
}